// Round 9
// baseline (89.012 us; speedup 1.0000x reference)
//
#include <hip/hip_runtime.h>
#include <math.h>

#define BISECT_ITERS 60
#define N_ROWS 131072
#define N_PAIRS (2 * N_ROWS)
#define BLOCK 256
#define NW (BLOCK / 64)

// float-rounded versions of python doubles (match numpy scalar->f32 cast)
#define E_CONST 2.71828182845904523536f       // float(np.e)
#define SMALL_THRESH 5.65685424949238019520f  // 4*sqrt(2)
#define LN2F 0.69314718055994530942f
// fp32 nearest of ln(1e-12) — np's safe_log at/below the clamp
#define LOG1EM12 -27.63102111592854820f

// ---------------------------------------------------------------------------
// Correctly-rounded fp32 natural log (double atanh-series, round once).
// Decision-point fallback path — gave absmax 0.0 vs numpy in round 3.
// ---------------------------------------------------------------------------
__device__ __forceinline__ float log_cr(float wc) {
    double d = (double)wc;
    long long b = __double_as_longlong(d);
    int e = (int)((b >> 52) & 0x7FF) - 1023;
    double m = __longlong_as_double((b & 0x000FFFFFFFFFFFFFLL) |
                                    0x3FF0000000000000LL);  // m in [1,2)
    if (m > 1.3333333333333333) {
        m *= 0.5;
        e += 1;
    }
    double s = (m - 1.0) / (m + 1.0);
    double s2 = s * s;
    double p = 1.0 / 17.0;
    p = fma(p, s2, 1.0 / 15.0);
    p = fma(p, s2, 1.0 / 13.0);
    p = fma(p, s2, 1.0 / 11.0);
    p = fma(p, s2, 1.0 / 9.0);
    p = fma(p, s2, 1.0 / 7.0);
    p = fma(p, s2, 1.0 / 5.0);
    p = fma(p, s2, 1.0 / 3.0);
    p = fma(p, s2, 1.0);
    double res = fma(2.0 * s, p, (double)e * 0.69314718055994530941723212145818);
    return (float)res;
}

__device__ __forceinline__ float safe_log_f(float w) {
    if (w <= 1e-12f) return LOG1EM12;  // == log_cr(1e-12), constant-folded
    return log_cr(w);
}

// ---------------------------------------------------------------------------
// Custom double exp (deg-12 Taylor after ln2 range reduction). rel err
// ~1e-16 -> rounds to the same fp32 bits as libm's exp (round 3: absmax 0.0
// with libm). Input |x| <= ~2 here; formula valid for |x| < 700.
// ---------------------------------------------------------------------------
__device__ __forceinline__ float exp_f32_cr(float xf) {
    double x = (double)xf;
    double kd = rint(x * 1.4426950408889634074);  // x/ln2
    double r = fma(-kd, 0.69314718055994528623, x);   // ln2_hi
    r = fma(-kd, 2.3190468138462995584e-17, r);       // ln2_lo
    double p = 1.0 / 479001600.0;       // 1/12!
    p = fma(p, r, 1.0 / 39916800.0);
    p = fma(p, r, 1.0 / 3628800.0);
    p = fma(p, r, 1.0 / 362880.0);
    p = fma(p, r, 1.0 / 40320.0);
    p = fma(p, r, 1.0 / 5040.0);
    p = fma(p, r, 1.0 / 720.0);
    p = fma(p, r, 1.0 / 120.0);
    p = fma(p, r, 1.0 / 24.0);
    p = fma(p, r, 1.0 / 6.0);
    p = fma(p, r, 0.5);
    p = fma(p, r, 1.0);
    p = fma(p, r, 1.0);
    long long k = (long long)kd;
    double scale = __longlong_as_double((k + 1023LL) << 52);
    return (float)(p * scale);
}

__device__ __forceinline__ float clip1f(float x) {
#pragma clang fp contract(off)
    return fminf(fmaxf(x, -1.0f), 1.0f);
}

__device__ __forceinline__ float sl1(float x) {  // smooth_l1, beta=1
#pragma clang fp contract(off)
    float d = fabsf(x);
    return (d < 1.0f) ? (0.5f * d) * d : d - 0.5f;
}

// cr eval: numpy op-order, IEEE fp32, no contraction
__device__ __forceinline__ float eps_f(float w, float wh, float lwp) {
#pragma clang fp contract(off)
    return sl1((w - wh) * 0.5f) + sl1(safe_log_f(w) - lwp);
}

__device__ __forceinline__ float eps_prime_cr(float w, float wh, float lwp) {
#pragma clang fp contract(off)
    float x = (w - wh) * 0.5f;
    float diff = safe_log_f(w) - lwp;
    return 0.5f * clip1f(x) + clip1f(diff) / fmaxf(w, 1e-12f);
}

__device__ __forceinline__ float sigma_cr(float w, float wh, float lwp) {
#pragma clang fp contract(off)
    return w * eps_prime_cr(w, wh, lwp);
}

// Fast native-log ln (<=~4e-6 abs err over the w range here)
__device__ __forceinline__ float nlogf(float w) {
    return LN2F * __builtin_amdgcn_logf(fmaxf(w, 1e-12f));
}

// Fast inner-loop sign of eps_prime (multiplied through by max(m,1e-12)>0).
__device__ __forceinline__ float epsp_sign(float m, float wh, float lwp) {
    float wm = fmaxf(m, 1e-12f);
    float x = (m - wh) * 0.5f;
    float diff = __builtin_fmaf(LN2F, __builtin_amdgcn_logf(wm), -lwp);
    return __builtin_fmaf(0.5f * clip1f(x), wm, clip1f(diff));
}

// ---------------------------------------------------------------------------
// Certified fast sign tests (+1/-1 provable, 0 => cr fallback required).
// ---------------------------------------------------------------------------
__device__ __forceinline__ int fast_epsp_sgn(float x, float wh, float lwp) {
    float wm = fmaxf(x, 1e-12f);
    float F = epsp_sign(x, wh, lwp);  // ~ wm * eps'(x)
    float tau = 2e-5f * (wm + 1.0f);
    if (F > tau) return 1;
    if (F < -tau) return -1;
    return 0;
}

__device__ __forceinline__ int fast_sigma_sgn(float x, float wh, float lwp) {
    float wm = fmaxf(x, 1e-12f);
    float F = epsp_sign(x, wh, lwp);
    float G = x * F;  // ~ wm * sigma(x)
    float tau = fabsf(x) * (2e-5f * (wm + 1.0f));
    if (G > tau) return 1;
    if (G < -tau) return -1;
    return 0;
}

// Fast eval (native log); err <= ~5e-6 + 1.2e-7*|E|
__device__ __forceinline__ float fast_eval(float w, float wh, float lwp) {
#pragma clang fp contract(off)
    return sl1((w - wh) * 0.5f) + sl1(nlogf(w) - lwp);
}

// Endpoint override decisions, certified-fast with cr fallback
__device__ __forceinline__ bool ov_e_le(float x, float wh, float lwp) {
    int s = fast_epsp_sgn(x, wh, lwp);
    if (s < 0) return true;
    if (s > 0) return false;
    return eps_prime_cr(x, wh, lwp) <= 0.0f;
}
__device__ __forceinline__ bool ov_e_ge(float x, float wh, float lwp) {
    int s = fast_epsp_sgn(x, wh, lwp);
    if (s > 0) return true;
    if (s < 0) return false;
    return eps_prime_cr(x, wh, lwp) >= 0.0f;
}
__device__ __forceinline__ bool ov_s_le(float x, float wh, float lwp) {
    int s = fast_sigma_sgn(x, wh, lwp);
    if (s < 0) return true;
    if (s > 0) return false;
    return sigma_cr(x, wh, lwp) <= 0.0f;
}
__device__ __forceinline__ bool ov_s_ge(float x, float wh, float lwp) {
    int s = fast_sigma_sgn(x, wh, lwp);
    if (s > 0) return true;
    if (s < 0) return false;
    return sigma_cr(x, wh, lwp) >= 0.0f;
}

// Certified argmin over 7 candidate/eval slots (1e30 marks invalid).
__device__ __forceinline__ float argmin7(const float* cands, const float* Ef,
                                         const bool* valid, float wh, float lwp) {
#pragma clang fp contract(off)
    int j = 0;
    float best = Ef[0];
#pragma unroll
    for (int k = 1; k < 7; ++k) {
        if (Ef[k] < best) { best = Ef[k]; j = k; }
    }
    bool need_cr = false;
#pragma unroll
    for (int k = 0; k < 7; ++k) {
        if (k == j) continue;
        float dl = 2e-5f + 2e-6f * (fabsf(best) + fabsf(Ef[k]));
        if (Ef[k] < best + dl &&
            fabsf(cands[k] - cands[j]) > 1e-4f * (1.0f + fabsf(cands[j])))
            need_cr = true;
    }
    if (need_cr) {
        float Ec[7];
#pragma unroll
        for (int k = 0; k < 7; ++k)
            Ec[k] = valid[k] ? eps_f(cands[k], wh, lwp) : 1e30f;
        j = 0;
        best = Ec[0];
#pragma unroll
        for (int k = 1; k < 7; ++k) {
            if (Ec[k] < best) { best = Ec[k]; j = k; }
        }
    }
    return cands[j];
}

// Convergence: frozen (np-exact state) OR width <= 1e-4 relative.
// eps is stationary at the root: a 1e-4 root shift moves eps by ~1e-8 —
// 2000x below the 2e-5 certified decision bands; output tolerance is 2.08.
__device__ __forceinline__ bool cvg(float u, float v, float m) {
    return (m == u) || (m == v) ||
           (fabsf(v - u) <= 1e-4f * fmaxf(1.0f, fabsf(m)));
}

// ---------------------------------------------------------------------------
// Per-pair parameters (fp32 IEEE, contract off — numpy bit-order)
// ---------------------------------------------------------------------------
struct PairP {
    float pd, po, td, to, a1r, b1r, a1l, b1l;
    int lt, rb;
};

__device__ __forceinline__ PairP load_pair(const float* __restrict__ pred,
                                           const float* __restrict__ target,
                                           const float* __restrict__ crop,
                                           const float* __restrict__ prop,
                                           const int* __restrict__ cases,
                                           int pair) {
#pragma clang fp contract(off)
    int row = pair >> 1, axis = pair & 1;
    int d_id = axis, o_id = axis + 2, r4 = row * 4;
    PairP P;
    P.pd = pred[r4 + d_id];
    P.po = exp_f32_cr(pred[r4 + o_id]);
    P.td = target[r4 + d_id];
    P.to = exp_f32_cr(target[r4 + o_id]);
    float p_d = prop[r4 + d_id];
    float p_o = prop[r4 + o_id];
    float ca = 0.5f * (p_d + p_o);
    float da = p_o - p_d;
    float crop_a = crop[r4 + axis];
    P.a1r = P.td - 0.5f * P.to;
    P.b1r = (crop_a - ca) / da;
    P.a1l = (-ca) / da;
    P.b1l = P.td + 0.5f * P.to;
    P.lt = cases[r4 + 2 * axis];
    P.rb = cases[r4 + 2 * axis + 1];
    return P;
}

// ---------------------------------------------------------------------------
// Unified solver: type is per-lane DATA, not control flow.
//   type 0 = branchB large (subs: c2,c3,c5,c6)
//   type 1 = branchB small (subs: c2,c3,c4; c6 slot dummied)
//   type 2 = branchA       (sub:  cA in the s2 slot; others dummied)
// ---------------------------------------------------------------------------
__device__ float solve_unified(int type, float wp, float wh, float w0, float lwp) {
#pragma clang fp contract(off)
    bool isA = (type == 2);
    bool small_ = (type == 1);
    float ewp = E_CONST * wp;
    float base = fmaxf(w0, fmaxf(wh - 2.0f, ewp));
    float disc = sqrtf(fmaxf(1.0f - 32.0f / fmaxf(wh * wh, 1e-12f), 0.0f));

    // s2: eps-prime bisection — B's c2, or A's cA bracket
    float u2 = isA ? fmaxf(w0, wh) : fmaxf(w0, wp);
    float v2 = isA ? wp : fminf(ewp, wh);
    // s3: eps-prime bisection — B's c3 (dummy for A)
    float u3 = fmaxf(fmaxf(w0, 2.0f), fmaxf(wh - 2.0f, ewp));
    float v3 = isA ? u3 : wh;
    // s4: sigma bisection — small's c4 or large's c5 (dummy for A)
    float u4 = base;
    float v4 = isA ? base
                   : (small_ ? fminf(E_CONST, wh)
                             : fminf(fminf(ewp, wh),
                                     (wh * 0.25f) * (1.0f + disc)));
    // s6: sigma bisection — large's c6 (dummy for A/small)
    float u6 = fmaxf(base, (wh * 0.25f) * (1.0f - disc));
    float v6 = (isA || small_) ? u6 : fminf(ewp, wh);

    float u02 = u2, v02 = v2, u03 = u3, v03 = v3;
    float u04 = u4, v04 = v4, u06 = u6, v06 = v6;

#pragma unroll 1
    for (int i = 0; i < BISECT_ITERS; ++i) {
        float m2 = (u2 + v2) * 0.5f;
        float m3 = (u3 + v3) * 0.5f;
        float m4 = (u4 + v4) * 0.5f;
        float m6 = (u6 + v6) * 0.5f;
        bool fr = cvg(u2, v2, m2) && cvg(u3, v3, m3) &&
                  cvg(u4, v4, m4) && cvg(u6, v6, m6);
        bool c2 = epsp_sign(m2, wh, lwp) >= 0.0f;
        bool c3 = epsp_sign(m3, wh, lwp) >= 0.0f;
        bool c4 = (m4 * epsp_sign(m4, wh, lwp)) >= 0.0f;
        bool c6 = (m6 * epsp_sign(m6, wh, lwp)) >= 0.0f;
        u2 = c2 ? u2 : m2; v2 = c2 ? m2 : v2;
        u3 = c3 ? u3 : m3; v3 = c3 ? m3 : v3;
        u4 = c4 ? u4 : m4; v4 = c4 ? m4 : v4;
        u6 = c6 ? u6 : m6; v6 = c6 ? m6 : v6;
        if (__all(fr)) break;
    }

    float r2 = (u2 + v2) * 0.5f;
    if (ov_e_le(v02, wh, lwp)) r2 = v02;
    if (ov_e_ge(u02, wh, lwp)) r2 = u02;
    float r3 = (u3 + v3) * 0.5f;
    if (ov_e_le(v03, wh, lwp)) r3 = v03;
    if (ov_e_ge(u03, wh, lwp)) r3 = u03;
    float r4 = (u4 + v4) * 0.5f;
    if (ov_s_le(v04, wh, lwp)) r4 = v04;
    if (ov_s_ge(u04, wh, lwp)) r4 = u04;
    float r6 = (u6 + v6) * 0.5f;
    if (ov_s_le(v06, wh, lwp)) r6 = v06;
    if (ov_s_ge(u06, wh, lwp)) r6 = u06;

    // slot4 = small's c4, slot5 = large's c5 — same register r4
    float cands[7] = {w0, wh, r2, r3, r4, r4, r6};
    bool valid[7] = {!isA, !isA, !isA, !isA,
                     small_, !isA && !small_, !isA && !small_};
    float Ef[7];
#pragma unroll
    for (int k = 0; k < 7; ++k)
        Ef[k] = valid[k] ? fast_eval(cands[k], wh, lwp) : 1e30f;
    float wB = argmin7(cands, Ef, valid, wh, lwp);
    return isA ? r2 : wB;
}

// ---------------------------------------------------------------------------
// Fused kernel: classify -> single LDS queue -> spread compacted solve
// (items strided across ALL waves for latency hiding) -> combine.
// ---------------------------------------------------------------------------
__global__ __launch_bounds__(BLOCK)
void cabb_fused_kernel(const float* __restrict__ pred,
                       const float* __restrict__ target,
                       const float* __restrict__ crop,
                       const float* __restrict__ prop,
                       const int* __restrict__ cases,
                       float* __restrict__ out) {
#pragma clang fp contract(off)
    __shared__ float q_wp[2 * BLOCK], q_wh[2 * BLOCK], q_w0[2 * BLOCK];
    __shared__ unsigned short q_code[2 * BLOCK];  // dest(12b) | type<<12
    __shared__ float s_res[2 * BLOCK];
    __shared__ int s_cnt[NW];

    int tid = threadIdx.x;
    int wid = tid >> 6;
    int lane = tid & 63;
    unsigned long long lower = (1ULL << lane) - 1ULL;
    int pair = blockIdx.x * BLOCK + tid;

    PairP P = load_pair(pred, target, crop, prop, cases, pair);

    bool need_b = P.lt && P.rb;
    bool need_l = P.lt && !P.rb;
    bool need_r = !P.lt && P.rb;

    // ---- classify into up to 2 items (type 0=Blarge, 1=Bsmall, 2=A) ----
    int it_type[2] = {-1, -1};
    float it_wp[2], it_wh[2], it_w0[2];
    unsigned short it_code[2];
    int nit = 0;

    if (need_r || need_l) {
        float wp = P.po;
        float wh = need_l ? 2.0f * (P.b1l - P.pd) : 2.0f * (P.pd - P.a1r);
        float w0 = need_l ? (P.b1l - P.a1l) : (P.b1r - P.a1r);
        bool bA = fmaxf(w0, wh) < wp;
        bool bB = fmaxf(w0, wp) < wh;
        if (bA || bB) {
            it_type[0] = bA ? 2 : (wh <= SMALL_THRESH ? 1 : 0);
            it_wp[0] = wp; it_wh[0] = wh; it_w0[0] = w0;
            it_code[0] = (unsigned short)(tid * 2);
            nit = 1;
        }
    } else if (need_b) {
        float wh1 = 2.0f * (P.pd - P.a1l);
        float wh2 = 2.0f * (P.b1r - P.pd);
        bool trivial = P.pd >= fmaxf(wh1, wh2);
        if (!trivial) {
            float w0 = P.b1r - P.a1l;
            for (int s = 0; s < 2; ++s) {
                float wh = s ? wh2 : wh1;
                bool bA = fmaxf(w0, wh) < P.pd;
                bool bB = fmaxf(w0, P.pd) < wh;
                if (bA || bB) {
                    it_type[nit] = bA ? 2 : (wh <= SMALL_THRESH ? 1 : 0);
                    it_wp[nit] = P.pd; it_wh[nit] = wh; it_w0[nit] = w0;
                    it_code[nit] = (unsigned short)(tid * 2 + s);
                    ++nit;
                }
            }
        }
    }

    // ---- single push round: ballot-prefix per wave, LDS-scan across waves ----
    bool h0 = it_type[0] >= 0;
    bool h1 = it_type[1] >= 0;
    unsigned long long mA = __ballot(h0);
    unsigned long long mB = __ballot(h1);
    int popA = __popcll(mA);
    if (lane == 0) s_cnt[wid] = popA + __popcll(mB);
    __syncthreads();
    int qbase = 0, nQ = 0;
#pragma unroll
    for (int w = 0; w < NW; ++w) {
        int c = s_cnt[w];
        if (w < wid) qbase += c;
        nQ += c;
    }
    if (h0) {
        int p = qbase + __popcll(mA & lower);
        q_wp[p] = it_wp[0]; q_wh[p] = it_wh[0]; q_w0[p] = it_w0[0];
        q_code[p] = (unsigned short)(it_code[0] | (it_type[0] << 12));
    }
    if (h1) {
        int p = qbase + popA + __popcll(mB & lower);
        q_wp[p] = it_wp[1]; q_wh[p] = it_wh[1]; q_w0[p] = it_w0[1];
        q_code[p] = (unsigned short)(it_code[1] | (it_type[1] << 12));
    }
    __syncthreads();

    // ---- spread compacted solve: item i -> wave (i%NW), lane (i/NW).
    // All waves participate (better latency hiding, earlier per-wave
    // freeze); pure scheduling change, per-lane cvg guarantee unchanged.
    for (int i = lane * NW + wid; i < nQ; i += BLOCK) {
        float wp = q_wp[i], wh = q_wh[i], w0 = q_w0[i];
        int cc = q_code[i];
        float lwp = safe_log_f(wp);
        s_res[cc & 0xFFF] = solve_unified(cc >> 12, wp, wh, w0, lwp);
    }
    __syncthreads();

    // ---- combine (predicates recomputed bit-identically) ----
    int row = pair >> 1, axis = pair & 1;
    int r4 = row * 4;
    float d_lab, w_lab;
    if (need_b) {
        float wh1 = 2.0f * (P.pd - P.a1l);
        float wh2 = 2.0f * (P.b1r - P.pd);
        bool trivial = P.pd >= fmaxf(wh1, wh2);
        if (trivial) {
            d_lab = P.pd;
            w_lab = P.pd;
        } else {
            float w0 = P.b1r - P.a1l;
            bool q1 = (fmaxf(w0, wh1) < P.pd) || (fmaxf(w0, P.pd) < wh1);
            bool q2 = (fmaxf(w0, wh2) < P.pd) || (fmaxf(w0, P.pd) < wh2);
            float s1 = q1 ? s_res[tid * 2] : w0;
            float s2 = q2 ? s_res[tid * 2 + 1] : w0;
            // pick1: certified fast compare, cr fallback
            float lwpf = nlogf(P.pd);
            float F1 = sl1((s1 - wh1) * 0.5f) + sl1(nlogf(s1) - lwpf);
            float F2 = sl1((s2 - wh2) * 0.5f) + sl1(nlogf(s2) - lwpf);
            float dl = 3e-5f + 2e-6f * (fabsf(F1) + fabsf(F2));
            bool pick1;
            if (F1 <= F2 - dl) {
                pick1 = true;
            } else if (F1 > F2 + dl) {
                pick1 = false;
            } else {
                float lwp = safe_log_f(P.pd);
                pick1 = eps_f(s1, wh1, lwp) <= eps_f(s2, wh2, lwp);
            }
            d_lab = pick1 ? (P.a1l + 0.5f * s1) : (P.b1r + 0.5f * s2);
            w_lab = pick1 ? s1 : s2;
        }
    } else if (need_l) {
        float wh = 2.0f * (P.b1l - P.pd);
        float w0 = P.b1l - P.a1l;
        bool q = (fmaxf(w0, wh) < P.po) || (fmaxf(w0, P.po) < wh);
        float s = q ? s_res[tid * 2] : w0;
        d_lab = P.b1l - 0.5f * s;
        w_lab = s;
    } else if (need_r) {
        float wh = 2.0f * (P.pd - P.a1r);
        float w0 = P.b1r - P.a1r;
        bool q = (fmaxf(w0, wh) < P.po) || (fmaxf(w0, P.po) < wh);
        float s = q ? s_res[tid * 2] : w0;
        d_lab = P.a1r + 0.5f * s;
        w_lab = s;
    } else {
        d_lab = P.td;
        w_lab = P.to;
    }

    out[r4 + axis] = d_lab;
    out[r4 + 2 + axis] = w_lab;
}

extern "C" void kernel_launch(void* const* d_in, const int* in_sizes, int n_in,
                              void* d_out, int out_size, void* d_ws, size_t ws_size,
                              hipStream_t stream) {
    // Inputs: img, pred, target, crop_shapes, proposal_list, cases, sampling_results
    const float* pred = (const float*)d_in[1];
    const float* target = (const float*)d_in[2];
    const float* crop = (const float*)d_in[3];
    const float* prop = (const float*)d_in[4];
    const int* cases = (const int*)d_in[5];
    float* out = (float*)d_out;

    cabb_fused_kernel<<<N_PAIRS / BLOCK, BLOCK, 0, stream>>>(
        pred, target, crop, prop, cases, out);
}

// Round 10
// 83.474 us; speedup vs baseline: 1.0664x; 1.0664x over previous
//
#include <hip/hip_runtime.h>
#include <math.h>

#define BISECT_ITERS 60
#define N_ROWS 131072
#define N_PAIRS (2 * N_ROWS)
#define BLOCK 512
#define NW (BLOCK / 64)

// float-rounded versions of python doubles (match numpy scalar->f32 cast)
#define E_CONST 2.71828182845904523536f       // float(np.e)
#define SMALL_THRESH 5.65685424949238019520f  // 4*sqrt(2)
#define LN2F 0.69314718055994530942f
// fp32 nearest of ln(1e-12) — np's safe_log at/below the clamp
#define LOG1EM12 -27.63102111592854820f

// ---------------------------------------------------------------------------
// Correctly-rounded fp32 natural log (double atanh-series, round once).
// Decision-point fallback path — gave absmax 0.0 vs numpy in round 3.
// ---------------------------------------------------------------------------
__device__ __forceinline__ float log_cr(float wc) {
    double d = (double)wc;
    long long b = __double_as_longlong(d);
    int e = (int)((b >> 52) & 0x7FF) - 1023;
    double m = __longlong_as_double((b & 0x000FFFFFFFFFFFFFLL) |
                                    0x3FF0000000000000LL);  // m in [1,2)
    if (m > 1.3333333333333333) {
        m *= 0.5;
        e += 1;
    }
    double s = (m - 1.0) / (m + 1.0);
    double s2 = s * s;
    double p = 1.0 / 17.0;
    p = fma(p, s2, 1.0 / 15.0);
    p = fma(p, s2, 1.0 / 13.0);
    p = fma(p, s2, 1.0 / 11.0);
    p = fma(p, s2, 1.0 / 9.0);
    p = fma(p, s2, 1.0 / 7.0);
    p = fma(p, s2, 1.0 / 5.0);
    p = fma(p, s2, 1.0 / 3.0);
    p = fma(p, s2, 1.0);
    double res = fma(2.0 * s, p, (double)e * 0.69314718055994530941723212145818);
    return (float)res;
}

__device__ __forceinline__ float safe_log_f(float w) {
    if (w <= 1e-12f) return LOG1EM12;  // == log_cr(1e-12), constant-folded
    return log_cr(w);
}

// ---------------------------------------------------------------------------
// Custom double exp (deg-12 Taylor after ln2 range reduction). rel err
// ~1e-16 -> rounds to the same fp32 bits as libm's exp (round 3: absmax 0.0
// with libm). Input |x| <= ~2 here; formula valid for |x| < 700.
// ---------------------------------------------------------------------------
__device__ __forceinline__ float exp_f32_cr(float xf) {
    double x = (double)xf;
    double kd = rint(x * 1.4426950408889634074);  // x/ln2
    double r = fma(-kd, 0.69314718055994528623, x);   // ln2_hi
    r = fma(-kd, 2.3190468138462995584e-17, r);       // ln2_lo
    double p = 1.0 / 479001600.0;       // 1/12!
    p = fma(p, r, 1.0 / 39916800.0);
    p = fma(p, r, 1.0 / 3628800.0);
    p = fma(p, r, 1.0 / 362880.0);
    p = fma(p, r, 1.0 / 40320.0);
    p = fma(p, r, 1.0 / 5040.0);
    p = fma(p, r, 1.0 / 720.0);
    p = fma(p, r, 1.0 / 120.0);
    p = fma(p, r, 1.0 / 24.0);
    p = fma(p, r, 1.0 / 6.0);
    p = fma(p, r, 0.5);
    p = fma(p, r, 1.0);
    p = fma(p, r, 1.0);
    long long k = (long long)kd;
    double scale = __longlong_as_double((k + 1023LL) << 52);
    return (float)(p * scale);
}

__device__ __forceinline__ float clip1f(float x) {
#pragma clang fp contract(off)
    return fminf(fmaxf(x, -1.0f), 1.0f);
}

__device__ __forceinline__ float sl1(float x) {  // smooth_l1, beta=1
#pragma clang fp contract(off)
    float d = fabsf(x);
    return (d < 1.0f) ? (0.5f * d) * d : d - 0.5f;
}

// cr eval: numpy op-order, IEEE fp32, no contraction
__device__ __forceinline__ float eps_f(float w, float wh, float lwp) {
#pragma clang fp contract(off)
    return sl1((w - wh) * 0.5f) + sl1(safe_log_f(w) - lwp);
}

__device__ __forceinline__ float eps_prime_cr(float w, float wh, float lwp) {
#pragma clang fp contract(off)
    float x = (w - wh) * 0.5f;
    float diff = safe_log_f(w) - lwp;
    return 0.5f * clip1f(x) + clip1f(diff) / fmaxf(w, 1e-12f);
}

__device__ __forceinline__ float sigma_cr(float w, float wh, float lwp) {
#pragma clang fp contract(off)
    return w * eps_prime_cr(w, wh, lwp);
}

// Fast native-log ln (<=~4e-6 abs err over the w range here)
__device__ __forceinline__ float nlogf(float w) {
    return LN2F * __builtin_amdgcn_logf(fmaxf(w, 1e-12f));
}

// Fast inner-loop sign of eps_prime (multiplied through by max(m,1e-12)>0).
__device__ __forceinline__ float epsp_sign(float m, float wh, float lwp) {
    float wm = fmaxf(m, 1e-12f);
    float x = (m - wh) * 0.5f;
    float diff = __builtin_fmaf(LN2F, __builtin_amdgcn_logf(wm), -lwp);
    return __builtin_fmaf(0.5f * clip1f(x), wm, clip1f(diff));
}

// ---------------------------------------------------------------------------
// Certified fast sign tests (+1/-1 provable, 0 => cr fallback required).
// ---------------------------------------------------------------------------
__device__ __forceinline__ int fast_epsp_sgn(float x, float wh, float lwp) {
    float wm = fmaxf(x, 1e-12f);
    float F = epsp_sign(x, wh, lwp);  // ~ wm * eps'(x)
    float tau = 2e-5f * (wm + 1.0f);
    if (F > tau) return 1;
    if (F < -tau) return -1;
    return 0;
}

__device__ __forceinline__ int fast_sigma_sgn(float x, float wh, float lwp) {
    float wm = fmaxf(x, 1e-12f);
    float F = epsp_sign(x, wh, lwp);
    float G = x * F;  // ~ wm * sigma(x)
    float tau = fabsf(x) * (2e-5f * (wm + 1.0f));
    if (G > tau) return 1;
    if (G < -tau) return -1;
    return 0;
}

// Fast eval (native log); err <= ~5e-6 + 1.2e-7*|E|
__device__ __forceinline__ float fast_eval(float w, float wh, float lwp) {
#pragma clang fp contract(off)
    return sl1((w - wh) * 0.5f) + sl1(nlogf(w) - lwp);
}

// Endpoint override decisions, certified-fast with cr fallback
__device__ __forceinline__ bool ov_e_le(float x, float wh, float lwp) {
    int s = fast_epsp_sgn(x, wh, lwp);
    if (s < 0) return true;
    if (s > 0) return false;
    return eps_prime_cr(x, wh, lwp) <= 0.0f;
}
__device__ __forceinline__ bool ov_e_ge(float x, float wh, float lwp) {
    int s = fast_epsp_sgn(x, wh, lwp);
    if (s > 0) return true;
    if (s < 0) return false;
    return eps_prime_cr(x, wh, lwp) >= 0.0f;
}
__device__ __forceinline__ bool ov_s_le(float x, float wh, float lwp) {
    int s = fast_sigma_sgn(x, wh, lwp);
    if (s < 0) return true;
    if (s > 0) return false;
    return sigma_cr(x, wh, lwp) <= 0.0f;
}
__device__ __forceinline__ bool ov_s_ge(float x, float wh, float lwp) {
    int s = fast_sigma_sgn(x, wh, lwp);
    if (s > 0) return true;
    if (s < 0) return false;
    return sigma_cr(x, wh, lwp) >= 0.0f;
}

// Certified argmin over 7 candidate/eval slots (1e30 marks invalid).
__device__ __forceinline__ float argmin7(const float* cands, const float* Ef,
                                         const bool* valid, float wh, float lwp) {
#pragma clang fp contract(off)
    int j = 0;
    float best = Ef[0];
#pragma unroll
    for (int k = 1; k < 7; ++k) {
        if (Ef[k] < best) { best = Ef[k]; j = k; }
    }
    bool need_cr = false;
#pragma unroll
    for (int k = 0; k < 7; ++k) {
        if (k == j) continue;
        float dl = 2e-5f + 2e-6f * (fabsf(best) + fabsf(Ef[k]));
        if (Ef[k] < best + dl &&
            fabsf(cands[k] - cands[j]) > 1e-4f * (1.0f + fabsf(cands[j])))
            need_cr = true;
    }
    if (need_cr) {
        float Ec[7];
#pragma unroll
        for (int k = 0; k < 7; ++k)
            Ec[k] = valid[k] ? eps_f(cands[k], wh, lwp) : 1e30f;
        j = 0;
        best = Ec[0];
#pragma unroll
        for (int k = 1; k < 7; ++k) {
            if (Ec[k] < best) { best = Ec[k]; j = k; }
        }
    }
    return cands[j];
}

// Convergence: frozen (np-exact state) OR width <= 1e-4 relative.
// eps is stationary at the root: a 1e-4 root shift moves eps by ~1e-8 —
// 2000x below the 2e-5 certified decision bands; output tolerance is 2.08.
__device__ __forceinline__ bool cvg(float u, float v, float m) {
    return (m == u) || (m == v) ||
           (fabsf(v - u) <= 1e-4f * fmaxf(1.0f, fabsf(m)));
}

// ---------------------------------------------------------------------------
// Per-pair parameters (fp32 IEEE, contract off — numpy bit-order)
// ---------------------------------------------------------------------------
struct PairP {
    float pd, po, td, to, a1r, b1r, a1l, b1l;
    int lt, rb;
};

__device__ __forceinline__ PairP load_pair(const float* __restrict__ pred,
                                           const float* __restrict__ target,
                                           const float* __restrict__ crop,
                                           const float* __restrict__ prop,
                                           const int* __restrict__ cases,
                                           int pair) {
#pragma clang fp contract(off)
    int row = pair >> 1, axis = pair & 1;
    int d_id = axis, o_id = axis + 2, r4 = row * 4;
    PairP P;
    P.pd = pred[r4 + d_id];
    P.po = exp_f32_cr(pred[r4 + o_id]);
    P.td = target[r4 + d_id];
    P.to = exp_f32_cr(target[r4 + o_id]);
    float p_d = prop[r4 + d_id];
    float p_o = prop[r4 + o_id];
    float ca = 0.5f * (p_d + p_o);
    float da = p_o - p_d;
    float crop_a = crop[r4 + axis];
    P.a1r = P.td - 0.5f * P.to;
    P.b1r = (crop_a - ca) / da;
    P.a1l = (-ca) / da;
    P.b1l = P.td + 0.5f * P.to;
    P.lt = cases[r4 + 2 * axis];
    P.rb = cases[r4 + 2 * axis + 1];
    return P;
}

// ---------------------------------------------------------------------------
// Unified solver: type is per-lane DATA, not control flow.
//   type 0 = branchB large (subs: c2,c3,c5,c6)
//   type 1 = branchB small (subs: c2,c3,c4; c6 slot dummied)
//   type 2 = branchA       (sub:  cA in the s2 slot; others dummied)
// ---------------------------------------------------------------------------
__device__ float solve_unified(int type, float wp, float wh, float w0, float lwp) {
#pragma clang fp contract(off)
    bool isA = (type == 2);
    bool small_ = (type == 1);
    float ewp = E_CONST * wp;
    float base = fmaxf(w0, fmaxf(wh - 2.0f, ewp));
    float disc = sqrtf(fmaxf(1.0f - 32.0f / fmaxf(wh * wh, 1e-12f), 0.0f));

    // s2: eps-prime bisection — B's c2, or A's cA bracket
    float u2 = isA ? fmaxf(w0, wh) : fmaxf(w0, wp);
    float v2 = isA ? wp : fminf(ewp, wh);
    // s3: eps-prime bisection — B's c3 (dummy for A)
    float u3 = fmaxf(fmaxf(w0, 2.0f), fmaxf(wh - 2.0f, ewp));
    float v3 = isA ? u3 : wh;
    // s4: sigma bisection — small's c4 or large's c5 (dummy for A)
    float u4 = base;
    float v4 = isA ? base
                   : (small_ ? fminf(E_CONST, wh)
                             : fminf(fminf(ewp, wh),
                                     (wh * 0.25f) * (1.0f + disc)));
    // s6: sigma bisection — large's c6 (dummy for A/small)
    float u6 = fmaxf(base, (wh * 0.25f) * (1.0f - disc));
    float v6 = (isA || small_) ? u6 : fminf(ewp, wh);

    float u02 = u2, v02 = v2, u03 = u3, v03 = v3;
    float u04 = u4, v04 = v4, u06 = u6, v06 = v6;

#pragma unroll 1
    for (int i = 0; i < BISECT_ITERS; ++i) {
        float m2 = (u2 + v2) * 0.5f;
        float m3 = (u3 + v3) * 0.5f;
        float m4 = (u4 + v4) * 0.5f;
        float m6 = (u6 + v6) * 0.5f;
        bool fr = cvg(u2, v2, m2) && cvg(u3, v3, m3) &&
                  cvg(u4, v4, m4) && cvg(u6, v6, m6);
        bool c2 = epsp_sign(m2, wh, lwp) >= 0.0f;
        bool c3 = epsp_sign(m3, wh, lwp) >= 0.0f;
        bool c4 = (m4 * epsp_sign(m4, wh, lwp)) >= 0.0f;
        bool c6 = (m6 * epsp_sign(m6, wh, lwp)) >= 0.0f;
        u2 = c2 ? u2 : m2; v2 = c2 ? m2 : v2;
        u3 = c3 ? u3 : m3; v3 = c3 ? m3 : v3;
        u4 = c4 ? u4 : m4; v4 = c4 ? m4 : v4;
        u6 = c6 ? u6 : m6; v6 = c6 ? m6 : v6;
        if (__all(fr)) break;
    }

    float r2 = (u2 + v2) * 0.5f;
    if (ov_e_le(v02, wh, lwp)) r2 = v02;
    if (ov_e_ge(u02, wh, lwp)) r2 = u02;
    float r3 = (u3 + v3) * 0.5f;
    if (ov_e_le(v03, wh, lwp)) r3 = v03;
    if (ov_e_ge(u03, wh, lwp)) r3 = u03;
    float r4 = (u4 + v4) * 0.5f;
    if (ov_s_le(v04, wh, lwp)) r4 = v04;
    if (ov_s_ge(u04, wh, lwp)) r4 = u04;
    float r6 = (u6 + v6) * 0.5f;
    if (ov_s_le(v06, wh, lwp)) r6 = v06;
    if (ov_s_ge(u06, wh, lwp)) r6 = u06;

    // slot4 = small's c4, slot5 = large's c5 — same register r4
    float cands[7] = {w0, wh, r2, r3, r4, r4, r6};
    bool valid[7] = {!isA, !isA, !isA, !isA,
                     small_, !isA && !small_, !isA && !small_};
    float Ef[7];
#pragma unroll
    for (int k = 0; k < 7; ++k)
        Ef[k] = valid[k] ? fast_eval(cands[k], wh, lwp) : 1e30f;
    float wB = argmin7(cands, Ef, valid, wh, lwp);
    return isA ? r2 : wB;
}

// ---------------------------------------------------------------------------
// Fused kernel: classify -> single LDS queue (one push round, one chunk
// ceiling) -> unified compacted solve (CHUNKED round-robin: dense 64-lane
// chunks minimize slow-lane contamination across waves) -> combine.
// ---------------------------------------------------------------------------
__global__ __launch_bounds__(BLOCK)
void cabb_fused_kernel(const float* __restrict__ pred,
                       const float* __restrict__ target,
                       const float* __restrict__ crop,
                       const float* __restrict__ prop,
                       const int* __restrict__ cases,
                       float* __restrict__ out) {
#pragma clang fp contract(off)
    __shared__ float q_wp[2 * BLOCK], q_wh[2 * BLOCK], q_w0[2 * BLOCK];
    __shared__ unsigned short q_code[2 * BLOCK];  // dest(12b) | type<<12
    __shared__ float s_res[2 * BLOCK];
    __shared__ int s_cnt[NW];

    int tid = threadIdx.x;
    int wid = tid >> 6;
    int lane = tid & 63;
    unsigned long long lower = (1ULL << lane) - 1ULL;
    int pair = blockIdx.x * BLOCK + tid;

    PairP P = load_pair(pred, target, crop, prop, cases, pair);

    bool need_b = P.lt && P.rb;
    bool need_l = P.lt && !P.rb;
    bool need_r = !P.lt && P.rb;

    // ---- classify into up to 2 items (type 0=Blarge, 1=Bsmall, 2=A) ----
    int it_type[2] = {-1, -1};
    float it_wp[2], it_wh[2], it_w0[2];
    unsigned short it_code[2];
    int nit = 0;

    if (need_r || need_l) {
        float wp = P.po;
        float wh = need_l ? 2.0f * (P.b1l - P.pd) : 2.0f * (P.pd - P.a1r);
        float w0 = need_l ? (P.b1l - P.a1l) : (P.b1r - P.a1r);
        bool bA = fmaxf(w0, wh) < wp;
        bool bB = fmaxf(w0, wp) < wh;
        if (bA || bB) {
            it_type[0] = bA ? 2 : (wh <= SMALL_THRESH ? 1 : 0);
            it_wp[0] = wp; it_wh[0] = wh; it_w0[0] = w0;
            it_code[0] = (unsigned short)(tid * 2);
            nit = 1;
        }
    } else if (need_b) {
        float wh1 = 2.0f * (P.pd - P.a1l);
        float wh2 = 2.0f * (P.b1r - P.pd);
        bool trivial = P.pd >= fmaxf(wh1, wh2);
        if (!trivial) {
            float w0 = P.b1r - P.a1l;
            for (int s = 0; s < 2; ++s) {
                float wh = s ? wh2 : wh1;
                bool bA = fmaxf(w0, wh) < P.pd;
                bool bB = fmaxf(w0, P.pd) < wh;
                if (bA || bB) {
                    it_type[nit] = bA ? 2 : (wh <= SMALL_THRESH ? 1 : 0);
                    it_wp[nit] = P.pd; it_wh[nit] = wh; it_w0[nit] = w0;
                    it_code[nit] = (unsigned short)(tid * 2 + s);
                    ++nit;
                }
            }
        }
    }

    // ---- single push round: ballot-prefix per wave, LDS-scan across waves ----
    bool h0 = it_type[0] >= 0;
    bool h1 = it_type[1] >= 0;
    unsigned long long mA = __ballot(h0);
    unsigned long long mB = __ballot(h1);
    int popA = __popcll(mA);
    if (lane == 0) s_cnt[wid] = popA + __popcll(mB);
    __syncthreads();
    int qbase = 0, nQ = 0;
#pragma unroll
    for (int w = 0; w < NW; ++w) {
        int c = s_cnt[w];
        if (w < wid) qbase += c;
        nQ += c;
    }
    if (h0) {
        int p = qbase + __popcll(mA & lower);
        q_wp[p] = it_wp[0]; q_wh[p] = it_wh[0]; q_w0[p] = it_w0[0];
        q_code[p] = (unsigned short)(it_code[0] | (it_type[0] << 12));
    }
    if (h1) {
        int p = qbase + popA + __popcll(mB & lower);
        q_wp[p] = it_wp[1]; q_wh[p] = it_wh[1]; q_w0[p] = it_w0[1];
        q_code[p] = (unsigned short)(it_code[1] | (it_type[1] << 12));
    }
    __syncthreads();

    // ---- unified compacted solve: dense chunked round-robin ----
    int chunks = (nQ + 63) >> 6;
    for (int c = wid; c < chunks; c += NW) {
        int i = (c << 6) + lane;
        if (i < nQ) {
            float wp = q_wp[i], wh = q_wh[i], w0 = q_w0[i];
            int cc = q_code[i];
            float lwp = safe_log_f(wp);
            s_res[cc & 0xFFF] = solve_unified(cc >> 12, wp, wh, w0, lwp);
        }
    }
    __syncthreads();

    // ---- combine (predicates recomputed bit-identically) ----
    int row = pair >> 1, axis = pair & 1;
    int r4 = row * 4;
    float d_lab, w_lab;
    if (need_b) {
        float wh1 = 2.0f * (P.pd - P.a1l);
        float wh2 = 2.0f * (P.b1r - P.pd);
        bool trivial = P.pd >= fmaxf(wh1, wh2);
        if (trivial) {
            d_lab = P.pd;
            w_lab = P.pd;
        } else {
            float w0 = P.b1r - P.a1l;
            bool q1 = (fmaxf(w0, wh1) < P.pd) || (fmaxf(w0, P.pd) < wh1);
            bool q2 = (fmaxf(w0, wh2) < P.pd) || (fmaxf(w0, P.pd) < wh2);
            float s1 = q1 ? s_res[tid * 2] : w0;
            float s2 = q2 ? s_res[tid * 2 + 1] : w0;
            // pick1: certified fast compare, cr fallback
            float lwpf = nlogf(P.pd);
            float F1 = sl1((s1 - wh1) * 0.5f) + sl1(nlogf(s1) - lwpf);
            float F2 = sl1((s2 - wh2) * 0.5f) + sl1(nlogf(s2) - lwpf);
            float dl = 3e-5f + 2e-6f * (fabsf(F1) + fabsf(F2));
            bool pick1;
            if (F1 <= F2 - dl) {
                pick1 = true;
            } else if (F1 > F2 + dl) {
                pick1 = false;
            } else {
                float lwp = safe_log_f(P.pd);
                pick1 = eps_f(s1, wh1, lwp) <= eps_f(s2, wh2, lwp);
            }
            d_lab = pick1 ? (P.a1l + 0.5f * s1) : (P.b1r + 0.5f * s2);
            w_lab = pick1 ? s1 : s2;
        }
    } else if (need_l) {
        float wh = 2.0f * (P.b1l - P.pd);
        float w0 = P.b1l - P.a1l;
        bool q = (fmaxf(w0, wh) < P.po) || (fmaxf(w0, P.po) < wh);
        float s = q ? s_res[tid * 2] : w0;
        d_lab = P.b1l - 0.5f * s;
        w_lab = s;
    } else if (need_r) {
        float wh = 2.0f * (P.pd - P.a1r);
        float w0 = P.b1r - P.a1r;
        bool q = (fmaxf(w0, wh) < P.po) || (fmaxf(w0, P.po) < wh);
        float s = q ? s_res[tid * 2] : w0;
        d_lab = P.a1r + 0.5f * s;
        w_lab = s;
    } else {
        d_lab = P.td;
        w_lab = P.to;
    }

    out[r4 + axis] = d_lab;
    out[r4 + 2 + axis] = w_lab;
}

extern "C" void kernel_launch(void* const* d_in, const int* in_sizes, int n_in,
                              void* d_out, int out_size, void* d_ws, size_t ws_size,
                              hipStream_t stream) {
    // Inputs: img, pred, target, crop_shapes, proposal_list, cases, sampling_results
    const float* pred = (const float*)d_in[1];
    const float* target = (const float*)d_in[2];
    const float* crop = (const float*)d_in[3];
    const float* prop = (const float*)d_in[4];
    const int* cases = (const int*)d_in[5];
    float* out = (float*)d_out;

    cabb_fused_kernel<<<N_PAIRS / BLOCK, BLOCK, 0, stream>>>(
        pred, target, crop, prop, cases, out);
}